// Round 6
// baseline (436.771 us; speedup 1.0000x reference)
//
#include <hip/hip_runtime.h>
#include <hip/hip_fp16.h>
#include <stdint.h>

#define OUT_F 4096
#define IN_F  4096
#define M_DIM 8192
#define K_DIM IN_F
#define N_DIM OUT_F
#define GROUPS (OUT_F * IN_F / 64)
#define NTRIP  (GROUPS * 8)
#define NPARAM (GROUPS * 2)
#define NKT    (K_DIM / 64)      // 64 K-tiles
#define NIT    (NKT / 2)         // 32 iterations

typedef __attribute__((ext_vector_type(4))) float f32x4;
typedef __attribute__((ext_vector_type(8))) short bf16x8;
typedef __attribute__((ext_vector_type(8))) unsigned short u16x8;

static __device__ __forceinline__ unsigned short f32_to_bf16(float f) {
    unsigned int u = __builtin_bit_cast(unsigned int, f);
    u += 0x7fffu + ((u >> 16) & 1u);
    return (unsigned short)(u >> 16);
}

// ---------------- params dtype detection (f16 vs f32 on device) ----------------
__global__ void flag_init(int* f) { f[0] = 0; }

__global__ __launch_bounds__(256) void detect_f16(const __half* __restrict__ p,
                                                  int* __restrict__ flag) {
    int big = 0;
    for (int i = blockIdx.x * 256 + threadIdx.x; i < NPARAM; i += 256 * 256) {
        float v = __half2float(p[i]);
        if (!(fabsf(v) < 1.0f)) big = 1;
    }
    if (big) atomicOr(flag, 1);
}

// ---------------- dequant: 3-bit packed -> bf16 W[N][K] row-major ----------------
__global__ __launch_bounds__(256) void dequant3(const int* __restrict__ pk,
                                                const void* __restrict__ params,
                                                const int* __restrict__ flag,
                                                unsigned short* __restrict__ W) {
    int t = blockIdx.x * 256 + threadIdx.x;
    int b0 = pk[3 * t + 0];
    int b1 = pk[3 * t + 1];
    int b2 = pk[3 * t + 2];
    int g = t >> 3;
    float lo, hi;
    if (flag[0] == 0) {
        const __half* p = (const __half*)params;
        lo = __half2float(p[2 * g + 0]);
        hi = __half2float(p[2 * g + 1]);
    } else {
        const float* p = (const float*)params;
        lo = p[2 * g + 0];
        hi = p[2 * g + 1];
    }
    float s = (hi - lo) * (1.0f / 7.0f);

    int q[8];
    q[0] = b0 & 7;
    q[1] = (b0 >> 3) & 7;
    q[2] = ((b0 >> 6) & 3) | ((b1 & 1) << 2);
    q[3] = (b1 >> 1) & 7;
    q[4] = (b1 >> 4) & 7;
    q[5] = ((b1 >> 7) & 1) | ((b2 & 3) << 1);
    q[6] = (b2 >> 2) & 7;
    q[7] = (b2 >> 5) & 7;

    u16x8 o;
#pragma unroll
    for (int j = 0; j < 8; j++) {
        float w = (float)q[j] * s + lo;
        o[j] = f32_to_bf16(w);
    }
    *(u16x8*)&W[8 * (size_t)t] = o;
}

// ---------------- x: f32 -> bf16 ----------------
__global__ __launch_bounds__(256) void cvt_x(const float* __restrict__ x,
                                             unsigned short* __restrict__ xb) {
    size_t t = (size_t)blockIdx.x * 256 + threadIdx.x;
    f32x4 a = *(const f32x4*)&x[8 * t];
    f32x4 b = *(const f32x4*)&x[8 * t + 4];
    u16x8 o;
#pragma unroll
    for (int j = 0; j < 4; j++) o[j] = f32_to_bf16(a[j]);
#pragma unroll
    for (int j = 0; j < 4; j++) o[4 + j] = f32_to_bf16(b[j]);
    *(u16x8*)&xb[8 * t] = o;
}

// ============ 256x256 8-phase GEMM, one-ahead register rotation ============
// 8 waves (2M x 4N), per-wave 128x64. LDS: buf0 = X tile (even), buf1 = Y (odd).
// Register sets: Aa, Ab (A), Ba, Bb (B). Every MFMA operand is ds_read >= 1
// phase before use; every ds_read targets registers whose last MFMA use is
// >= 1 phase earlier (WAR-safe vs in-flight MFMA).
// Stage slots: ph1->Y.B, ph4->X'.A, ph5->X'.B, ph8->Y'.A.
// vmcnt ledger: ph2 VMW(4) [drain Y.A], ph3 VMW(0) [drain Y.B],
//               ph6 VMW(4) [drain X'.A], ph7 VMW(0) [drain X'.B].
// launch_bounds (512,1): 512-reg/wave cap -> ~254 regs fit WITHOUT spill
// (R5's (512,2) capped at 256 total and spilled: +270MB scratch traffic).

#define READ_A_SET(dst, P, half) do { _Pragma("unroll") for (int m2_ = 0; m2_ < 4; ++m2_) { \
    const char* p_ = (P) + (half) * 8192 + m2_ * 2048; \
    dst[m2_][0] = *(const bf16x8*)(p_ + cb0); \
    dst[m2_][1] = *(const bf16x8*)(p_ + cb1); } } while (0)

#define READ_B_SET(dst, P, half) do { _Pragma("unroll") for (int n2_ = 0; n2_ < 2; ++n2_) { \
    const char* p_ = (P) + (half) * 4096 + n2_ * 2048; \
    dst[n2_][0] = *(const bf16x8*)(p_ + cb0); \
    dst[n2_][1] = *(const bf16x8*)(p_ + cb1); } } while (0)

#define MFMA_QS(As, Bs, miq, niq) do { __builtin_amdgcn_s_setprio(1); \
  _Pragma("unroll") for (int m2_ = 0; m2_ < 4; ++m2_) \
  _Pragma("unroll") for (int n2_ = 0; n2_ < 2; ++n2_) { \
    acc[(miq)*4+m2_][(niq)*2+n2_] = __builtin_amdgcn_mfma_f32_16x16x32_bf16(As[m2_][0], Bs[n2_][0], acc[(miq)*4+m2_][(niq)*2+n2_], 0,0,0); \
    acc[(miq)*4+m2_][(niq)*2+n2_] = __builtin_amdgcn_mfma_f32_16x16x32_bf16(As[m2_][1], Bs[n2_][1], acc[(miq)*4+m2_][(niq)*2+n2_], 0,0,0); } \
  __builtin_amdgcn_s_setprio(0); } while (0)

// stage one operand tile (4 gload_lds): scalar base (uniform) + per-lane voff
#define STAGE_OP(ldsbase, Gb, kt) do { \
  _Pragma("unroll") for (int h_ = 0; h_ < 2; ++h_) \
  _Pragma("unroll") for (int p_ = 0; p_ < 2; ++p_) { \
    const char* gu_ = (Gb) + (size_t)(kt) * 128 + (size_t)((h_*128 + p_*64) * 8192); \
    unsigned short* l_ = (ldsbase) + h_*8192 + p_*4096 + w*512; \
    __builtin_amdgcn_global_load_lds((const __attribute__((address_space(1))) unsigned int*)(gu_ + voff), \
        (__attribute__((address_space(3))) unsigned int*)l_, 16, 0, 0); } } while (0)

#define BAR() asm volatile("s_barrier" ::: "memory")
#define VMW(n) asm volatile("s_waitcnt vmcnt(" #n ")" ::: "memory")

__global__ __launch_bounds__(512, 1) void gemm8(const unsigned short* __restrict__ A,
                                                const unsigned short* __restrict__ B,
                                                const float* __restrict__ bias,
                                                float* __restrict__ C) {
    __shared__ unsigned short sh[2][2][16384];   // 128 KiB

    int bid = blockIdx.x;
    int swz = (bid & 7) * 64 + (bid >> 3);       // bijective XCD swizzle (nwg=512)
    int bm = swz >> 4, bn = swz & 15;            // 32 x 16 tiles
    const int row0 = bm * 256, col0 = bn * 256;

    const int t = threadIdx.x;
    const int lane = t & 63;
    const int w = t >> 6;
    const int wm = w >> 2, wn = w & 3;           // 2 x 4 waves, each 128x64

    // staging: per-lane voffset (loop-invariant), scalar bases per call
    const int l_hi = lane >> 3, l_lo = lane & 7;
    const int sg_row = w * 8 + l_hi;
    const int sg_col = (l_lo ^ l_hi) * 8;        // pre-swizzled source col
    const int voff = sg_row * 8192 + sg_col * 2; // bytes

    // fragment read addressing
    const int fr = lane & 15;
    const int kg = lane >> 4;
    const int swzb = (lane & 7) << 4;
    const int cb0 = (kg * 16) ^ swzb;
    const int cb1 = (64 + kg * 16) ^ swzb;
    const int arow_b = (wm * 128 + fr) * 128;
    const int brow_b = (wn * 64 + fr) * 128;

    const char* GAb = (const char*)A + (size_t)row0 * 8192;
    const char* GBb = (const char*)B + (size_t)col0 * 8192;

    const char* ldsAx = (const char*)&sh[0][0][0] + arow_b;
    const char* ldsBx = (const char*)&sh[0][1][0] + brow_b;
    const char* ldsAy = (const char*)&sh[1][0][0] + arow_b;
    const char* ldsBy = (const char*)&sh[1][1][0] + brow_b;

    f32x4 acc[8][4] = {};
    bf16x8 Aa[4][2], Ab[4][2], Ba[2][2], Bb[2][2];

    // prologue: X(buf0) <- tile0 A,B ; Y(buf1) <- tile1 A
    STAGE_OP((unsigned short*)&sh[0][0][0], GAb, 0);
    STAGE_OP((unsigned short*)&sh[0][1][0], GBb, 0);
    STAGE_OP((unsigned short*)&sh[1][0][0], GAb, 1);
    VMW(4);                     // X.A, X.B complete; Y.A in flight
    BAR();
    READ_A_SET(Aa, ldsAx, 0);   // prime ph1 operands
    READ_B_SET(Ba, ldsBx, 0);

    for (int it = 0; it < NIT; ++it) {
        const int ktx = 2 * it;
        const bool pf = (it + 1 < NIT);

        // ph1: X q(0,0)[Aa,Ba]; read Bb<-X.B1 (for ph2); stage Y.B
        READ_B_SET(Bb, ldsBx, 1);
        STAGE_OP((unsigned short*)&sh[1][1][0], GBb, ktx + 1);
        BAR(); MFMA_QS(Aa, Ba, 0, 0); BAR();
        // ph2: X q(0,1)[Aa,Bb]; read Ab<-X.A1 (for ph3); drain Y.A
        READ_A_SET(Ab, ldsAx, 1);
        VMW(4);
        BAR(); MFMA_QS(Aa, Bb, 0, 1); BAR();
        // ph3: X q(1,1)[Ab,Bb]; drain Y.B
        VMW(0);
        BAR(); MFMA_QS(Ab, Bb, 1, 1); BAR();
        // ph4: X q(1,0)[Ab,Ba]; read Aa<-Y.A0, Bb<-Y.B1 (for ph5); stage X'.A
        READ_A_SET(Aa, ldsAy, 0);
        READ_B_SET(Bb, ldsBy, 1);
        if (pf) STAGE_OP((unsigned short*)&sh[0][0][0], GAb, ktx + 2);
        BAR(); MFMA_QS(Ab, Ba, 1, 0); BAR();
        // ph5: Y q(0,1)[Aa,Bb]; read Ba<-Y.B0 (for ph6); stage X'.B
        READ_B_SET(Ba, ldsBy, 0);
        if (pf) STAGE_OP((unsigned short*)&sh[0][1][0], GBb, ktx + 2);
        BAR(); MFMA_QS(Aa, Bb, 0, 1); BAR();
        // ph6: Y q(0,0)[Aa,Ba]; read Ab<-Y.A1 (for ph7); drain X'.A
        READ_A_SET(Ab, ldsAy, 1);
        VMW(4);
        BAR(); MFMA_QS(Aa, Ba, 0, 0); BAR();
        // ph7: Y q(1,0)[Ab,Ba]; read Aa<-X'.A0 (for next ph1); drain X'.B
        if (pf) READ_A_SET(Aa, ldsAx, 0);
        VMW(0);
        BAR(); MFMA_QS(Ab, Ba, 1, 0); BAR();
        // ph8: Y q(1,1)[Ab,Bb]; read Ba<-X'.B0 (for next ph1); stage Y'.A
        if (pf) READ_B_SET(Ba, ldsBx, 0);
        if (pf) STAGE_OP((unsigned short*)&sh[1][0][0], GAb, ktx + 3);
        BAR(); MFMA_QS(Ab, Bb, 1, 1); BAR();
    }

    // epilogue: C/D layout col=lane&15, row=(lane>>4)*4+j; fuse bias
    const int crow = kg * 4;
    const int ccol = fr;
#pragma unroll
    for (int mi = 0; mi < 8; ++mi) {
#pragma unroll
        for (int ni = 0; ni < 4; ++ni) {
            int col = col0 + wn * 64 + ni * 16 + ccol;
            float bv = bias[col];
#pragma unroll
            for (int j = 0; j < 4; ++j) {
                int rw = row0 + wm * 128 + mi * 16 + crow + j;
                C[(size_t)rw * N_DIM + col] = acc[mi][ni][j] + bv;
            }
        }
    }
}

__global__ void ws_guard(float* out, float v) { out[0] = v; }

extern "C" void kernel_launch(void* const* d_in, const int* in_sizes, int n_in,
                              void* d_out, int out_size, void* d_ws, size_t ws_size,
                              hipStream_t stream) {
    const float* x      = (const float*)d_in[0];
    const int*   pk     = (const int*)d_in[1];
    const void*  params = (const void*)d_in[2];
    const float* bias   = (const float*)d_in[3];
    float* out = (float*)d_out;

    const size_t needW = (size_t)OUT_F * IN_F * 2;
    const size_t needX = (size_t)M_DIM * IN_F * 2;
    const size_t needF = 256;
    if (ws_size < needW + needX + needF) {
        ws_guard<<<1, 1, 0, stream>>>(out, 1.0e6f + (float)(ws_size >> 20));
        return;
    }
    unsigned short* W  = (unsigned short*)d_ws;
    unsigned short* Xb = (unsigned short*)((char*)d_ws + needW);
    int*            fl = (int*)((char*)d_ws + needW + needX);

    flag_init<<<1, 1, 0, stream>>>(fl);
    detect_f16<<<256, 256, 0, stream>>>((const __half*)params, fl);
    dequant3<<<NTRIP / 256, 256, 0, stream>>>(pk, params, fl, W);
    cvt_x<<<(int)(((size_t)M_DIM * IN_F / 8) / 256), 256, 0, stream>>>(x, Xb);
    gemm8<<<(M_DIM / 256) * (N_DIM / 256), 512, 0, stream>>>(Xb, W, bias, out);
}

// Round 7
// 326.468 us; speedup vs baseline: 1.3379x; 1.3379x over previous
//
#include <hip/hip_runtime.h>
#include <hip/hip_fp16.h>
#include <stdint.h>

#define OUT_F 4096
#define IN_F  4096
#define M_DIM 8192
#define K_DIM IN_F
#define N_DIM OUT_F
#define GROUPS (OUT_F * IN_F / 64)
#define NTRIP  (GROUPS * 8)
#define NPARAM (GROUPS * 2)
#define NIT    (K_DIM / 128)     // 32 iterations, 2 K-tiles (BK=64) each

typedef __attribute__((ext_vector_type(4))) float f32x4;
typedef __attribute__((ext_vector_type(8))) short bf16x8;
typedef __attribute__((ext_vector_type(8))) unsigned short u16x8;

static __device__ __forceinline__ unsigned short f32_to_bf16(float f) {
    unsigned int u = __builtin_bit_cast(unsigned int, f);
    u += 0x7fffu + ((u >> 16) & 1u);
    return (unsigned short)(u >> 16);
}

// ---------------- params dtype detection (f16 vs f32 on device) ----------------
__global__ void flag_init(int* f) { f[0] = 0; }

__global__ __launch_bounds__(256) void detect_f16(const __half* __restrict__ p,
                                                  int* __restrict__ flag) {
    int big = 0;
    for (int i = blockIdx.x * 256 + threadIdx.x; i < NPARAM; i += 256 * 256) {
        float v = __half2float(p[i]);
        if (!(fabsf(v) < 1.0f)) big = 1;
    }
    if (big) atomicOr(flag, 1);
}

// ---------------- dequant: 3-bit packed -> bf16 W[N][K] row-major ----------------
__global__ __launch_bounds__(256) void dequant3(const int* __restrict__ pk,
                                                const void* __restrict__ params,
                                                const int* __restrict__ flag,
                                                unsigned short* __restrict__ W) {
    int t = blockIdx.x * 256 + threadIdx.x;
    int b0 = pk[3 * t + 0];
    int b1 = pk[3 * t + 1];
    int b2 = pk[3 * t + 2];
    int g = t >> 3;
    float lo, hi;
    if (flag[0] == 0) {
        const __half* p = (const __half*)params;
        lo = __half2float(p[2 * g + 0]);
        hi = __half2float(p[2 * g + 1]);
    } else {
        const float* p = (const float*)params;
        lo = p[2 * g + 0];
        hi = p[2 * g + 1];
    }
    float s = (hi - lo) * (1.0f / 7.0f);

    int q[8];
    q[0] = b0 & 7;
    q[1] = (b0 >> 3) & 7;
    q[2] = ((b0 >> 6) & 3) | ((b1 & 1) << 2);
    q[3] = (b1 >> 1) & 7;
    q[4] = (b1 >> 4) & 7;
    q[5] = ((b1 >> 7) & 1) | ((b2 & 3) << 1);
    q[6] = (b2 >> 2) & 7;
    q[7] = (b2 >> 5) & 7;

    u16x8 o;
#pragma unroll
    for (int j = 0; j < 8; j++) {
        float w = (float)q[j] * s + lo;
        o[j] = f32_to_bf16(w);
    }
    *(u16x8*)&W[8 * (size_t)t] = o;
}

// ---------------- x: f32 -> bf16 ----------------
__global__ __launch_bounds__(256) void cvt_x(const float* __restrict__ x,
                                             unsigned short* __restrict__ xb) {
    size_t t = (size_t)blockIdx.x * 256 + threadIdx.x;
    f32x4 a = *(const f32x4*)&x[8 * t];
    f32x4 b = *(const f32x4*)&x[8 * t + 4];
    u16x8 o;
#pragma unroll
    for (int j = 0; j < 4; j++) o[j] = f32_to_bf16(a[j]);
#pragma unroll
    for (int j = 0; j < 4; j++) o[4 + j] = f32_to_bf16(b[j]);
    *(u16x8*)&xb[8 * t] = o;
}

// ===== 256x128 4-window GEMM, one-ahead register rotation, low reg pressure =====
// 8 waves (2M x 4N), per-wave 128x32 -> acc = 64 AGPR (fits 256-reg/wave cap of a
// 512-thread block with frag sets Aa/Ab/Bx/By = 96 VGPR; total ~180, no spill).
// LDS 96 KiB: per buf {A: 256x64 (32KB), B: 128x64 (16KB)}, dbuf x2.
// T2 swizzle: phys_byte = logical ^ ((row&7)<<4) via pre-swizzled global source.
// 4 windows/iter (X-h0, X-h1, Y-h0, Y-h1), 16 MFMA each, ONE barrier per window.
// Reads in window p are for window p+1 (reg-independent of current MFMA).
// Stage slots: P2 -> X'(A4+B2), P4 -> Y'(A4+B2). VMW(0) end-P1 (drain Y, aged 1+
// window), end-P3 (drain X'). LDS-region WAR: >=2 barriers read->restage.

#define READ_AH(dst, b, h) do { _Pragma("unroll") for (int m2_ = 0; m2_ < 4; ++m2_) { \
    const char* p_ = shb + (b) * 49152 + arow_b + ((h) * 4 + m2_) * 2048; \
    dst[m2_][0] = *(const bf16x8*)(p_ + cb0); \
    dst[m2_][1] = *(const bf16x8*)(p_ + cb1); } } while (0)

#define READ_BT(dst, b) do { _Pragma("unroll") for (int n_ = 0; n_ < 2; ++n_) { \
    const char* p_ = shb + (b) * 49152 + 32768 + brow_b + n_ * 2048; \
    dst[n_][0] = *(const bf16x8*)(p_ + cb0); \
    dst[n_][1] = *(const bf16x8*)(p_ + cb1); } } while (0)

#define MFMA_H(h, As, Bs) do { __builtin_amdgcn_s_setprio(1); \
  _Pragma("unroll") for (int m2_ = 0; m2_ < 4; ++m2_) \
  _Pragma("unroll") for (int n_ = 0; n_ < 2; ++n_) { \
    acc[(h)*4+m2_][n_] = __builtin_amdgcn_mfma_f32_16x16x32_bf16(As[m2_][0], Bs[n_][0], acc[(h)*4+m2_][n_], 0,0,0); \
    acc[(h)*4+m2_][n_] = __builtin_amdgcn_mfma_f32_16x16x32_bf16(As[m2_][1], Bs[n_][1], acc[(h)*4+m2_][n_], 0,0,0); } \
  __builtin_amdgcn_s_setprio(0); } while (0)

// A tile: 4 chunks of 64 rows; B tile: 2 chunks (global row stride 8192 B)
#define STAGE_A(b, kt) do { _Pragma("unroll") for (int c_ = 0; c_ < 4; ++c_) { \
    const char* g_ = GAb + (size_t)(kt) * 128 + (size_t)(c_ * 64) * 8192; \
    unsigned short* l_ = &sh[(b) * 24576 + c_ * 4096 + w * 512]; \
    __builtin_amdgcn_global_load_lds((const __attribute__((address_space(1))) unsigned int*)(g_ + voff), \
        (__attribute__((address_space(3))) unsigned int*)l_, 16, 0, 0); } } while (0)

#define STAGE_B(b, kt) do { _Pragma("unroll") for (int c_ = 0; c_ < 2; ++c_) { \
    const char* g_ = GBb + (size_t)(kt) * 128 + (size_t)(c_ * 64) * 8192; \
    unsigned short* l_ = &sh[(b) * 24576 + 16384 + c_ * 4096 + w * 512]; \
    __builtin_amdgcn_global_load_lds((const __attribute__((address_space(1))) unsigned int*)(g_ + voff), \
        (__attribute__((address_space(3))) unsigned int*)l_, 16, 0, 0); } } while (0)

#define BAR() asm volatile("s_barrier" ::: "memory")
#define VMW(n) asm volatile("s_waitcnt vmcnt(" #n ")" ::: "memory")

__global__ __launch_bounds__(512, 1) void gemm4(const unsigned short* __restrict__ A,
                                                const unsigned short* __restrict__ B,
                                                const float* __restrict__ bias,
                                                float* __restrict__ C) {
    __shared__ unsigned short sh[2 * 24576];     // 96 KiB

    // bijective XCD swizzle: nwg = 1024, cpx = 128
    int bid = blockIdx.x;
    int swz = (bid & 7) * 128 + (bid >> 3);
    int bm = swz >> 5, bn = swz & 31;            // 32 x 32 tiles
    const int row0 = bm * 256, col0 = bn * 128;

    const int t = threadIdx.x;
    const int lane = t & 63;
    const int w = t >> 6;
    const int wm = w >> 2, wn = w & 3;           // 2 x 4 waves, each 128x32

    // staging: per-lane voffset (pre-swizzled source col)
    const int l_hi = lane >> 3, l_lo = lane & 7;
    const int voff = (w * 8 + l_hi) * 8192 + ((l_lo ^ l_hi) * 16);

    // fragment read addressing
    const int fr = lane & 15;
    const int kg = lane >> 4;
    const int swzb = (lane & 7) << 4;
    const int cb0 = (kg * 16) ^ swzb;
    const int cb1 = (64 + kg * 16) ^ swzb;
    const int arow_b = (wm * 128 + fr) * 128;
    const int brow_b = (wn * 32 + fr) * 128;

    const char* GAb = (const char*)A + (size_t)row0 * 8192;
    const char* GBb = (const char*)B + (size_t)col0 * 8192;
    const char* shb = (const char*)sh;

    f32x4 acc[8][2] = {};
    bf16x8 Aa[4][2], Ab[4][2], Bx[2][2], By[2][2];

    // prologue: stage X (tile0) + Y (tile1); prime Aa<-X.A0, Bx<-X.B
    STAGE_A(0, 0); STAGE_B(0, 0);
    STAGE_A(1, 1); STAGE_B(1, 1);
    VMW(6);                      // X.A, X.B landed; Y in flight
    BAR();
    READ_AH(Aa, 0, 0);
    READ_BT(Bx, 0);

    for (int it = 0; it < NIT; ++it) {
        const int ktx = 2 * it;
        const bool pf = (it + 1 < NIT);

        // P1: MFMA X-h0 [Aa,Bx]; read Ab<-X.A1; drain Y (aged >=1 window)
        READ_AH(Ab, 0, 1);
        MFMA_H(0, Aa, Bx);
        VMW(0);
        BAR();
        // P2: MFMA X-h1 [Ab,Bx]; read Aa<-Y.A0, By<-Y.B; stage X'
        READ_AH(Aa, 1, 0);
        READ_BT(By, 1);
        if (pf) { STAGE_A(0, ktx + 2); STAGE_B(0, ktx + 2); }
        MFMA_H(1, Ab, Bx);
        BAR();
        // P3: MFMA Y-h0 [Aa,By]; read Ab<-Y.A1; drain X'
        READ_AH(Ab, 1, 1);
        MFMA_H(0, Aa, By);
        VMW(0);
        BAR();
        // P4: MFMA Y-h1 [Ab,By]; read Aa<-X'.A0, Bx<-X'.B; stage Y'
        if (pf) {
            READ_AH(Aa, 0, 0);
            READ_BT(Bx, 0);
            STAGE_A(1, ktx + 3); STAGE_B(1, ktx + 3);
        }
        MFMA_H(1, Ab, By);
        BAR();
    }

    // epilogue: C/D layout col=lane&15, row=(lane>>4)*4+j; fuse bias
    const int crow = kg * 4;
    const int ccol = fr;
#pragma unroll
    for (int mi = 0; mi < 8; ++mi) {
#pragma unroll
        for (int ni = 0; ni < 2; ++ni) {
            int col = col0 + wn * 32 + ni * 16 + ccol;
            float bv = bias[col];
#pragma unroll
            for (int j = 0; j < 4; ++j) {
                int rw = row0 + wm * 128 + mi * 16 + crow + j;
                C[(size_t)rw * N_DIM + col] = acc[mi][ni][j] + bv;
            }
        }
    }
}

__global__ void ws_guard(float* out, float v) { out[0] = v; }

extern "C" void kernel_launch(void* const* d_in, const int* in_sizes, int n_in,
                              void* d_out, int out_size, void* d_ws, size_t ws_size,
                              hipStream_t stream) {
    const float* x      = (const float*)d_in[0];
    const int*   pk     = (const int*)d_in[1];
    const void*  params = (const void*)d_in[2];
    const float* bias   = (const float*)d_in[3];
    float* out = (float*)d_out;

    const size_t needW = (size_t)OUT_F * IN_F * 2;
    const size_t needX = (size_t)M_DIM * IN_F * 2;
    const size_t needF = 256;
    if (ws_size < needW + needX + needF) {
        ws_guard<<<1, 1, 0, stream>>>(out, 1.0e6f + (float)(ws_size >> 20));
        return;
    }
    unsigned short* W  = (unsigned short*)d_ws;
    unsigned short* Xb = (unsigned short*)((char*)d_ws + needW);
    int*            fl = (int*)((char*)d_ws + needW + needX);

    flag_init<<<1, 1, 0, stream>>>(fl);
    detect_f16<<<256, 256, 0, stream>>>((const __half*)params, fl);
    dequant3<<<NTRIP / 256, 256, 0, stream>>>(pk, params, fl, W);
    cvt_x<<<(int)(((size_t)M_DIM * IN_F / 8) / 256), 256, 0, stream>>>(x, Xb);
    gemm4<<<(M_DIM / 256) * (N_DIM / 128), 512, 0, stream>>>(Xb, W, bias, out);
}